// Round 3
// baseline (291.594 us; speedup 1.0000x reference)
//
#include <hip/hip_runtime.h>

typedef __attribute__((ext_vector_type(8))) short bf16x8;
typedef __attribute__((ext_vector_type(4))) float f32x4;

#define B_  2
#define S_  2048
#define DM  512
#define KD  256
#define HD  32
#define NH  8

__device__ __forceinline__ float bf2f(ushort u) {
    return __uint_as_float(((uint)u) << 16);
}
__device__ __forceinline__ ushort f2bf(float f) {
    uint x = __float_as_uint(f);
    return (ushort)((x + 0x7fffu + ((x >> 16) & 1u)) >> 16);  // RNE
}

// Detect whether inputs are bf16 (flag=1) or fp32 (flag=0) by exponent-field
// statistics of Q's first 256 ushorts. (R1 evidence: inputs are fp32 — this
// detector stays as cheap insurance.)
__global__ void detect_dtype(const ushort* __restrict__ q, int* __restrict__ flag)
{
    if (threadIdx.x == 0 && blockIdx.x == 0) {
        int cnt = 0;
        for (int i = 0; i < 256; ++i) {
            int e = (q[i] >> 7) & 0xFF;
            if (e >= 100 && e <= 133) ++cnt;
        }
        *flag = (cnt >= 230) ? 1 : 0;
    }
}

// ---------------- QKV projection: [4096,512] @ [512,256] + bias -> [B,H,S,32] bf16
__global__ __launch_bounds__(256) void qkv_proj(
    const void* __restrict__ Q, const void* __restrict__ K, const void* __restrict__ V,
    const void* __restrict__ Wq, const void* __restrict__ bq,
    const void* __restrict__ Wk, const void* __restrict__ bk,
    const void* __restrict__ Wv, const void* __restrict__ bv,
    const int* __restrict__ flag,
    ushort* __restrict__ qh, ushort* __restrict__ kh, ushort* __restrict__ vh)
{
    const void *X, *W, *bias; ushort* out;
    int which = blockIdx.y;
    if (which == 0)      { X = Q; W = Wq; bias = bq; out = qh; }
    else if (which == 1) { X = K; W = Wk; bias = bk; out = kh; }
    else                 { X = V; W = Wv; bias = bv; out = vh; }
    int isbf = *flag;

    int wave = threadIdx.x >> 6, lane = threadIdx.x & 63;
    int l16 = lane & 15, quad = lane >> 4;
    int tile = blockIdx.x * 4 + wave;      // 256 m-tiles x 16 n-tiles = 4096
    int mt = tile >> 4, nt = tile & 15;
    int m0 = mt * 16, n0 = nt * 16;

    f32x4 acc = {0.f, 0.f, 0.f, 0.f};
    for (int ks = 0; ks < DM; ks += 32) {
        bf16x8 a, b;
        if (isbf) {
            a = *(const bf16x8*)((const ushort*)X + (m0 + l16) * DM + ks + quad * 8);
            const ushort* wp = (const ushort*)W + (ks + quad * 8) * KD + n0 + l16;
            #pragma unroll
            for (int j = 0; j < 8; ++j) b[j] = (short)wp[j * KD];
        } else {
            const float* af = (const float*)X + (m0 + l16) * DM + ks + quad * 8;
            #pragma unroll
            for (int j = 0; j < 8; ++j) a[j] = (short)f2bf(af[j]);
            const float* wp = (const float*)W + (ks + quad * 8) * KD + n0 + l16;
            #pragma unroll
            for (int j = 0; j < 8; ++j) b[j] = (short)f2bf(wp[j * KD]);
        }
        acc = __builtin_amdgcn_mfma_f32_16x16x32_bf16(a, b, acc, 0, 0, 0);
    }
    float bs = isbf ? bf2f(((const ushort*)bias)[n0 + l16]) : ((const float*)bias)[n0 + l16];
    int n = n0 + l16, h = n >> 5, d = n & 31;
    #pragma unroll
    for (int r = 0; r < 4; ++r) {
        int rg = m0 + quad * 4 + r;
        int bb = rg >> 11, ss = rg & 2047;
        out[(((bb * NH + h) * S_ + ss) << 5) + d] = f2bf(acc[r] + bs);
    }
}

// ---------------- Flash attention: per wave = 16 Q rows of one (b,h)
__global__ __launch_bounds__(256) void attn(
    const ushort* __restrict__ qh, const ushort* __restrict__ kh,
    const ushort* __restrict__ vh, const void* __restrict__ maskp,
    const int* __restrict__ flag, ushort* __restrict__ ctx)
{
    __shared__ __align__(16) short ldsP[4][16][32];
    int isbf = *flag;
    int wave = threadIdx.x >> 6, lane = threadIdx.x & 63;
    int l16 = lane & 15, quad = lane >> 4;
    int bh = blockIdx.x >> 5;                 // 16 (b,h) pairs
    int qt = (blockIdx.x & 31) * 4 + wave;    // 128 q-tiles per (b,h)
    int b = bh >> 3, h = bh & 7;
    int q0 = qt * 16;
    const ushort* qb = qh + bh * S_ * HD;
    const ushort* kb = kh + bh * S_ * HD;
    const ushort* vb = vh + bh * S_ * HD;
    const ushort* mbb = (const ushort*)maskp + (size_t)b * S_ * S_;
    const float*  mbf = (const float*)maskp  + (size_t)b * S_ * S_;

    bf16x8 aq = *(const bf16x8*)(qb + (q0 + l16) * HD + quad * 8);

    f32x4 O0 = {0, 0, 0, 0}, O1 = {0, 0, 0, 0};
    const f32x4 zero = {0, 0, 0, 0};
    float m_[4] = {-1e30f, -1e30f, -1e30f, -1e30f};
    float l_[4] = {0, 0, 0, 0};

    for (int k0 = 0; k0 < S_; k0 += 32) {
        bf16x8 bk0 = *(const bf16x8*)(kb + (k0 + l16) * HD + quad * 8);
        bf16x8 bk1 = *(const bf16x8*)(kb + (k0 + 16 + l16) * HD + quad * 8);
        f32x4 S0 = __builtin_amdgcn_mfma_f32_16x16x32_bf16(aq, bk0, zero, 0, 0, 0);
        f32x4 S1 = __builtin_amdgcn_mfma_f32_16x16x32_bf16(aq, bk1, zero, 0, 0, 0);

        float s0[4], s1[4], p0[4], p1[4];
        #pragma unroll
        for (int r = 0; r < 4; ++r) {
            size_t mo = (size_t)(q0 + quad * 4 + r) * S_ + k0;
            float mv0 = isbf ? bf2f(mbb[mo + l16])      : mbf[mo + l16];
            float mv1 = isbf ? bf2f(mbb[mo + 16 + l16]) : mbf[mo + 16 + l16];
            s0[r] = S0[r] * 0.0625f + mv0;
            s1[r] = S1[r] * 0.0625f + mv1;
        }
        #pragma unroll
        for (int r = 0; r < 4; ++r) {
            float t = fmaxf(s0[r], s1[r]);
            #pragma unroll
            for (int off = 8; off; off >>= 1) t = fmaxf(t, __shfl_xor(t, off, 16));
            float mn = fmaxf(m_[r], t);
            float al = __expf(m_[r] - mn);
            p0[r] = __expf(s0[r] - mn);
            p1[r] = __expf(s1[r] - mn);
            float rs = p0[r] + p1[r];
            #pragma unroll
            for (int off = 8; off; off >>= 1) rs += __shfl_xor(rs, off, 16);
            l_[r] = l_[r] * al + rs;
            m_[r] = mn;
            O0[r] *= al; O1[r] *= al;
            ldsP[wave][quad * 4 + r][l16]      = (short)f2bf(p0[r]);
            ldsP[wave][quad * 4 + r][16 + l16] = (short)f2bf(p1[r]);
        }
        __syncthreads();   // C-layout -> A-layout round trip through LDS
        bf16x8 aP = *(const bf16x8*)(&ldsP[wave][l16][quad * 8]);
        bf16x8 bv0, bv1;
        const ushort* vp = vb + (k0 + quad * 8) * HD;
        #pragma unroll
        for (int j = 0; j < 8; ++j) {
            bv0[j] = (short)vp[j * HD + l16];
            bv1[j] = (short)vp[j * HD + 16 + l16];
        }
        O0 = __builtin_amdgcn_mfma_f32_16x16x32_bf16(aP, bv0, O0, 0, 0, 0);
        O1 = __builtin_amdgcn_mfma_f32_16x16x32_bf16(aP, bv1, O1, 0, 0, 0);
        __syncthreads();
    }
    #pragma unroll
    for (int r = 0; r < 4; ++r) {
        float inv = 1.0f / l_[r];
        int rg = q0 + quad * 4 + r;
        ushort* crow = ctx + ((size_t)(b * S_ + rg)) * KD + h * HD;
        crow[l16]      = f2bf(O0[r] * inv);
        crow[16 + l16] = f2bf(O1[r] * inv);
    }
}

// ---------------- Output projection: [4096,256] @ [256,512] + bo -> FP32 out
__global__ __launch_bounds__(256) void out_proj(
    const ushort* __restrict__ ctx, const void* __restrict__ Wo,
    const void* __restrict__ bo, const int* __restrict__ flag,
    float* __restrict__ out)
{
    int isbf = *flag;
    int wave = threadIdx.x >> 6, lane = threadIdx.x & 63;
    int l16 = lane & 15, quad = lane >> 4;
    int tile = blockIdx.x * 4 + wave;   // 256 m-tiles x 32 n-tiles = 8192
    int mt = tile >> 5, nt = tile & 31;
    int m0 = mt * 16, n0 = nt * 16;
    f32x4 acc = {0, 0, 0, 0};
    const ushort* arow = ctx + (m0 + l16) * KD;
    for (int ks = 0; ks < KD; ks += 32) {
        bf16x8 a = *(const bf16x8*)(arow + ks + quad * 8);
        bf16x8 b;
        if (isbf) {
            const ushort* wp = (const ushort*)Wo + (ks + quad * 8) * DM + n0 + l16;
            #pragma unroll
            for (int j = 0; j < 8; ++j) b[j] = (short)wp[j * DM];
        } else {
            const float* wp = (const float*)Wo + (ks + quad * 8) * DM + n0 + l16;
            #pragma unroll
            for (int j = 0; j < 8; ++j) b[j] = (short)f2bf(wp[j * DM]);
        }
        acc = __builtin_amdgcn_mfma_f32_16x16x32_bf16(a, b, acc, 0, 0, 0);
    }
    float bs = isbf ? bf2f(((const ushort*)bo)[n0 + l16]) : ((const float*)bo)[n0 + l16];
    #pragma unroll
    for (int r = 0; r < 4; ++r) {
        out[(size_t)(m0 + quad * 4 + r) * DM + n0 + l16] = acc[r] + bs;  // fp32 store
    }
}

extern "C" void kernel_launch(void* const* d_in, const int* in_sizes, int n_in,
                              void* d_out, int out_size, void* d_ws, size_t ws_size,
                              hipStream_t stream)
{
    const void* V    = d_in[0];
    const void* Q    = d_in[1];
    const void* K    = d_in[2];
    const void* mask = d_in[3];
    const void* Wq = d_in[4];  const void* bq = d_in[5];
    const void* Wk = d_in[6];  const void* bk = d_in[7];
    const void* Wv = d_in[8];  const void* bv = d_in[9];
    const void* Wo = d_in[10]; const void* bo = d_in[11];
    float* out = (float*)d_out;

    int* flagp  = (int*)d_ws;
    ushort* qh  = (ushort*)d_ws + 128;            // [B,H,S,32] bf16
    ushort* kh  = qh + B_ * NH * S_ * HD;
    ushort* vh  = kh + B_ * NH * S_ * HD;
    ushort* ctx = vh + B_ * NH * S_ * HD;         // [B*S, 256] bf16

    detect_dtype<<<1, 64, 0, stream>>>((const ushort*)Q, flagp);
    qkv_proj<<<dim3(1024, 3), 256, 0, stream>>>(Q, K, V, Wq, bq, Wk, bk, Wv, bv, flagp, qh, kh, vh);
    attn<<<512, 256, 0, stream>>>(qh, kh, vh, mask, flagp, ctx);
    out_proj<<<2048, 256, 0, stream>>>(ctx, Wo, bo, flagp, out);
}